// Round 1
// baseline (1046.401 us; speedup 1.0000x reference)
//
#include <hip/hip_runtime.h>
#include <hip/hip_bf16.h>
#include <math.h>

// ---------------- workspace layout (bytes) ----------------
// P0: 16 MiB  conv1 out (4,64,128,128) -> later conv3 out -> later fich_t (4,64,64,128)
// P1: 16 MiB  conv2 out (4,64,128,128) -> later conv4 out / fich (4,128,64,64)
// P2:  4 MiB  maxpool out (4,64,64,64)
// DS:  512 KiB down_seg (4,8,64,64)
// IT:  768 KiB img normalized transposed (4,128,128,3)
// ST:  4 KiB  stats: meanF[128], rstdF[128], meanI[3], rstdI[3]
// AC:  512 B  accumulators: numV[32], denV[32], numI[32], denI[32]
#define OFF_P0 0
#define OFF_P1 16777216
#define OFF_P2 33554432
#define OFF_DS 37748736
#define OFF_IT 38273024
#define OFF_ST 39059456
#define OFF_AC 39063552

// ---------------- conv 3x3 SAME + bias + relu ----------------
// block = 256 threads = 16x16 output pixels; each thread computes 16 output
// channels (acc[16]); input staged in LDS 4 cin at a time; weights via
// block-uniform indices (scalar loads, separate SMEM pipe).
__global__ __launch_bounds__(256) void conv3x3_relu_k(
    const float* __restrict__ in, const float* __restrict__ w,
    const float* __restrict__ b, float* __restrict__ out,
    int N, int Cin, int Cout, int H, int W)
{
    const int TW = W >> 4, TH = H >> 4, OCG = Cout >> 4;
    int bid = blockIdx.x;
    int txt = bid % TW; bid /= TW;
    int tyt = bid % TH; bid /= TH;
    int ocg = bid % OCG; bid /= OCG;
    int n = bid;
    int x0 = txt * 16, y0 = tyt * 16;
    int tid = threadIdx.x;
    int tx = tid & 15, ty = tid >> 4;
    int ox = x0 + tx, oy = y0 + ty;

    __shared__ float lds[4][18][18];
    float acc[16];
#pragma unroll
    for (int i = 0; i < 16; ++i) acc[i] = 0.f;

    for (int c0 = 0; c0 < Cin; c0 += 4) {
        int cb = Cin - c0; if (cb > 4) cb = 4;
        __syncthreads();
        for (int i = tid; i < cb * 324; i += 256) {
            int cc = i / 324;
            int rem = i - cc * 324;
            int r = rem / 18;
            int col = rem - r * 18;
            int y = y0 - 1 + r, x = x0 - 1 + col;
            float v = 0.f;
            if (y >= 0 && y < H && x >= 0 && x < W)
                v = in[((size_t)(n * Cin + c0 + cc) * H + y) * W + x];
            lds[cc][r][col] = v;
        }
        __syncthreads();
#pragma unroll
        for (int cc = 0; cc < 4; ++cc) {
            if (cc >= cb) break;
            float i00 = lds[cc][ty + 0][tx + 0];
            float i01 = lds[cc][ty + 0][tx + 1];
            float i02 = lds[cc][ty + 0][tx + 2];
            float i10 = lds[cc][ty + 1][tx + 0];
            float i11 = lds[cc][ty + 1][tx + 1];
            float i12 = lds[cc][ty + 1][tx + 2];
            float i20 = lds[cc][ty + 2][tx + 0];
            float i21 = lds[cc][ty + 2][tx + 1];
            float i22 = lds[cc][ty + 2][tx + 2];
            const float* wp = w + ((size_t)(ocg * 16) * Cin + (c0 + cc)) * 9;
#pragma unroll
            for (int oc = 0; oc < 16; ++oc) {
                const float* wq = wp + (size_t)oc * Cin * 9;
                float a = acc[oc];
                a = fmaf(wq[0], i00, a);
                a = fmaf(wq[1], i01, a);
                a = fmaf(wq[2], i02, a);
                a = fmaf(wq[3], i10, a);
                a = fmaf(wq[4], i11, a);
                a = fmaf(wq[5], i12, a);
                a = fmaf(wq[6], i20, a);
                a = fmaf(wq[7], i21, a);
                a = fmaf(wq[8], i22, a);
                acc[oc] = a;
            }
        }
    }
#pragma unroll
    for (int oc = 0; oc < 16; ++oc) {
        float v = acc[oc] + b[ocg * 16 + oc];
        v = fmaxf(v, 0.f);
        out[((size_t)(n * Cout + ocg * 16 + oc) * H + oy) * W + ox] = v;
    }
}

// ---------------- 2x2 pools ----------------
__global__ __launch_bounds__(256) void maxpool2_k(const float* __restrict__ in,
                                                  float* __restrict__ out, int total)
{
    int tid = blockIdx.x * 256 + threadIdx.x;
    if (tid >= total) return;
    int wo = tid & 63, ho = (tid >> 6) & 63, ch = tid >> 12;
    const float* p = in + (size_t)ch * 16384 + (size_t)(ho * 2) * 128 + wo * 2;
    out[tid] = fmaxf(fmaxf(p[0], p[1]), fmaxf(p[128], p[129]));
}

__global__ __launch_bounds__(256) void avgpool2_k(const float* __restrict__ in,
                                                  float* __restrict__ out, int total)
{
    int tid = blockIdx.x * 256 + threadIdx.x;
    if (tid >= total) return;
    int wo = tid & 63, ho = (tid >> 6) & 63, ch = tid >> 12;
    const float* p = in + (size_t)ch * 16384 + (size_t)(ho * 2) * 128 + wo * 2;
    out[tid] = 0.25f * ((p[0] + p[1]) + (p[128] + p[129]));
}

// ---------------- batchnorm stats (training mode, biased var) ----------------
__global__ __launch_bounds__(256) void bn_stats_k(const float* __restrict__ x,
                                                  float* __restrict__ stats,
                                                  int C, int HW, int N)
{
    int c = blockIdx.x, tid = threadIdx.x;
    int M = N * HW;
    double s = 0.0, s2 = 0.0;
    for (int i = tid; i < M; i += 256) {
        int n = i / HW, r = i - n * HW;
        float v = x[((size_t)(n * C + c)) * HW + r];
        s += v;
        s2 += (double)v * (double)v;
    }
    __shared__ double ls[256], ls2[256];
    ls[tid] = s; ls2[tid] = s2;
    __syncthreads();
    for (int st = 128; st > 0; st >>= 1) {
        if (tid < st) { ls[tid] += ls[tid + st]; ls2[tid] += ls2[tid + st]; }
        __syncthreads();
    }
    if (tid == 0) {
        double mean = ls[0] / M;
        double var = ls2[0] / M - mean * mean;
        stats[c] = (float)mean;
        stats[C + c] = (float)(1.0 / sqrt(var + 1e-5));
    }
}

// ---------------- normalize + transpose fich: (4,128,64,64)->(4,64,64,128) ----
__global__ __launch_bounds__(256) void norm_transpose_f_k(
    const float* __restrict__ x, const float* __restrict__ stats,
    float* __restrict__ xt)
{
    int bid = blockIdx.x;           // n(4) x h(64) x ct(4) x wt(2)
    int wt = bid & 1; bid >>= 1;
    int ct = bid & 3; bid >>= 2;
    int h = bid & 63; bid >>= 6;
    int n = bid;
    int tx = threadIdx.x & 31, ty = threadIdx.x >> 5;
    __shared__ float lds[32][33];
    int c0 = ct * 32, w0 = wt * 32;
#pragma unroll
    for (int i = 0; i < 4; ++i) {
        int c = c0 + ty + i * 8;
        float v = x[(((size_t)n * 128 + c) * 64 + h) * 64 + (w0 + tx)];
        lds[ty + i * 8][tx] = (v - stats[c]) * stats[128 + c];
    }
    __syncthreads();
#pragma unroll
    for (int i = 0; i < 4; ++i) {
        int wcol = w0 + ty + i * 8;
        xt[(((size_t)(n * 64) + h) * 64 + wcol) * 128 + c0 + tx] = lds[tx][ty + i * 8];
    }
}

// ---------------- normalize + transpose images: (4,3,128,128)->(4,128,128,3) --
__global__ __launch_bounds__(256) void norm_transpose_i_k(
    const float* __restrict__ x, const float* __restrict__ stats,
    float* __restrict__ it)
{
    int tid = blockIdx.x * 256 + threadIdx.x;   // 65536 = 4*128*128
    int n = tid >> 14;
    int hw = tid & 16383;
#pragma unroll
    for (int c = 0; c < 3; ++c) {
        float v = x[(((size_t)n * 3 + c) << 14) + hw];
        it[(size_t)tid * 3 + c] = (v - stats[c]) * stats[3 + c];
    }
}

// ---------------- zero accumulators ----------------
__global__ void zero_k(float* acc)
{
    if (threadIdx.x < 128) acc[threadIdx.x] = 0.f;
}

// ---------------- modularity on VGG features (C=128, 64x64, sigma=0.02) ------
// one wave per pixel; lanes split 128 channels as float2; butterfly-reduce d2.
__global__ __launch_bounds__(256) void modularity64_k(
    const float* __restrict__ xt,   // (4,64,64,128)
    const float* __restrict__ seg,  // (4,8,64,64)
    float* __restrict__ acc)        // [0..31] num, [32..63] den
{
    const float inv2s2 = 1.0f / (2.0f * 0.02f * 0.02f); // 1250
    int wave = threadIdx.x >> 6, lane = threadIdx.x & 63;
    int bid = blockIdx.x;           // n(4) x hq(32) x wq(32)
    int wq = bid & 31; bid >>= 5;
    int hq = bid & 31; bid >>= 5;
    int n = bid;
    int h = hq * 2 + (wave >> 1);
    int w = wq * 2 + (wave & 1);

    const float2* cp = (const float2*)(xt + ((size_t)((n * 64 + h) * 64 + w)) * 128);
    float2 c = cp[lane];
    float w1 = 0.f;
    float numk = 0.f;

    for (int di = -2; di <= 2; ++di) {
        int h2 = h + di;
        if (h2 < 0 || h2 >= 64) continue;
        for (int dj = -2; dj <= 2; ++dj) {
            int w2 = w + dj;
            if (w2 < 0 || w2 >= 64) continue;
            const float2* np = (const float2*)(xt + ((size_t)((n * 64 + h2) * 64 + w2)) * 128);
            float2 v = np[lane];
            float dx = c.x - v.x, dy = c.y - v.y;
            float d2 = fmaf(dy, dy, dx * dx);
#pragma unroll
            for (int s = 32; s > 0; s >>= 1) d2 += __shfl_xor(d2, s, 64);
            float wgt = expf(-d2 * inv2s2);
            w1 += wgt;
            if (lane < 8) {
                float s2 = seg[((size_t)(n * 8 + lane) * 64 + h2) * 64 + w2];
                numk = fmaf(s2, wgt, numk);
            }
        }
    }
    if (lane < 8) {
        float sc = seg[((size_t)(n * 8 + lane) * 64 + h) * 64 + w];
        atomicAdd(&acc[n * 8 + lane], numk * sc);
        atomicAdd(&acc[32 + n * 8 + lane], w1 * sc);
    }
}

// ---------------- modularity on images (C=3, 128x128, sigma=0.2) -------------
// one thread per pixel; wave-reduce the 16 (num_k, den_k) partials, lane0 atomics.
__global__ __launch_bounds__(256) void modularity128_k(
    const float* __restrict__ it,   // (4,128,128,3)
    const float* __restrict__ seg,  // (4,8,128,128)
    float* __restrict__ acc)        // [64..95] num, [96..127] den
{
    const float inv2s2 = 1.0f / (2.0f * 0.2f * 0.2f); // 12.5
    int tid = blockIdx.x * 256 + threadIdx.x;  // 65536
    int lane = threadIdx.x & 63;
    int w = tid & 127;
    int h = (tid >> 7) & 127;
    int n = tid >> 14;

    const float* cp = it + (size_t)tid * 3;
    float c0 = cp[0], c1 = cp[1], c2 = cp[2];
    float segc[8], num[8];
#pragma unroll
    for (int k = 0; k < 8; ++k) {
        segc[k] = seg[((size_t)(n * 8 + k) * 128 + h) * 128 + w];
        num[k] = 0.f;
    }
    float w1 = 0.f;

    for (int di = -2; di <= 2; ++di) {
        int h2 = h + di;
        if (h2 < 0 || h2 >= 128) continue;
        for (int dj = -2; dj <= 2; ++dj) {
            int w2 = w + dj;
            if (w2 < 0 || w2 >= 128) continue;
            const float* vp = it + ((size_t)((n * 128 + h2) * 128 + w2)) * 3;
            float d0 = c0 - vp[0], d1 = c1 - vp[1], d2v = c2 - vp[2];
            float d2 = fmaf(d2v, d2v, fmaf(d1, d1, d0 * d0));
            float wgt = expf(-d2 * inv2s2);
            w1 += wgt;
            const float* sp = seg + ((size_t)(n * 8) * 128 + h2) * 128 + w2;
#pragma unroll
            for (int k = 0; k < 8; ++k)
                num[k] = fmaf(sp[(size_t)k * 16384], wgt, num[k]);
        }
    }

    // wave-level reduction of 16 partial sums, then one atomic per value
    float val;
#pragma unroll
    for (int k = 0; k < 8; ++k) {
        val = num[k] * segc[k];
#pragma unroll
        for (int s = 32; s > 0; s >>= 1) val += __shfl_xor(val, s, 64);
        if (lane == 0) atomicAdd(&acc[64 + n * 8 + k], val);
        val = w1 * segc[k];
#pragma unroll
        for (int s = 32; s > 0; s >>= 1) val += __shfl_xor(val, s, 64);
        if (lane == 0) atomicAdd(&acc[96 + n * 8 + k], val);
    }
}

// ---------------- finalize: loss = (sum relV + sum relI)/64 ------------------
__global__ void finalize_k(const float* __restrict__ acc, float* __restrict__ out)
{
    int l = threadIdx.x;  // 64 threads
    float v = 0.f;
    if (l < 32) v = acc[l] / acc[32 + l] + acc[64 + l] / acc[96 + l];
#pragma unroll
    for (int s = 32; s > 0; s >>= 1) v += __shfl_xor(v, s, 64);
    if (l == 0) out[0] = v * (1.0f / 64.0f);
}

extern "C" void kernel_launch(void* const* d_in, const int* in_sizes, int n_in,
                              void* d_out, int out_size, void* d_ws, size_t ws_size,
                              hipStream_t stream)
{
    const float* images = (const float*)d_in[0];
    const float* seg    = (const float*)d_in[1];
    const float* w1 = (const float*)d_in[2]; const float* b1 = (const float*)d_in[3];
    const float* w2 = (const float*)d_in[4]; const float* b2 = (const float*)d_in[5];
    const float* w3 = (const float*)d_in[6]; const float* b3 = (const float*)d_in[7];
    const float* w4 = (const float*)d_in[8]; const float* b4 = (const float*)d_in[9];
    float* out = (float*)d_out;
    char* ws = (char*)d_ws;
    float* P0 = (float*)(ws + OFF_P0);
    float* P1 = (float*)(ws + OFF_P1);
    float* P2 = (float*)(ws + OFF_P2);
    float* DS = (float*)(ws + OFF_DS);
    float* IT = (float*)(ws + OFF_IT);
    float* ST = (float*)(ws + OFF_ST);
    float* AC = (float*)(ws + OFF_AC);

    // VGG stem
    conv3x3_relu_k<<<1024, 256, 0, stream>>>(images, w1, b1, P0, 4, 3, 64, 128, 128);
    conv3x3_relu_k<<<1024, 256, 0, stream>>>(P0, w2, b2, P1, 4, 64, 64, 128, 128);
    maxpool2_k<<<4096, 256, 0, stream>>>(P1, P2, 1048576);
    conv3x3_relu_k<<<512, 256, 0, stream>>>(P2, w3, b3, P0, 4, 64, 128, 64, 64);
    conv3x3_relu_k<<<512, 256, 0, stream>>>(P0, w4, b4, P1, 4, 128, 128, 64, 64);

    // batchnorm stats (fich in P1; images)
    bn_stats_k<<<128, 256, 0, stream>>>(P1, ST, 128, 4096, 4);
    bn_stats_k<<<3, 256, 0, stream>>>(images, ST + 256, 3, 16384, 4);

    // normalize + transpose for channel-contiguous modularity reads
    norm_transpose_f_k<<<2048, 256, 0, stream>>>(P1, ST, P0);
    norm_transpose_i_k<<<256, 256, 0, stream>>>(images, ST + 256, IT);

    // downsample segmentation 128 -> 64
    avgpool2_k<<<512, 256, 0, stream>>>(seg, DS, 131072);

    // modularity terms
    zero_k<<<1, 128, 0, stream>>>(AC);
    modularity64_k<<<4096, 256, 0, stream>>>(P0, DS, AC);
    modularity128_k<<<256, 256, 0, stream>>>(IT, seg, AC);

    finalize_k<<<1, 64, 0, stream>>>(AC, out);
}